// Round 2
// baseline (541.689 us; speedup 1.0000x reference)
//
#include <hip/hip_runtime.h>
#include <hip/hip_bf16.h>

// ---------------------------------------------------------------------------
// Fully-fused SwinV2 window attention, one workgroup per window.
//   B=4096 windows, N=64 tokens, DIM=256, H=8 heads, HD=32, NW=1024 masks.
// Round 2: LDS 155KB -> 79KB for 2 blocks/CU. Per-head q/k/v live in a
// per-wave 4.5KB scratch (q,k transit to regs; vT resides). QK^T fully
// register-resident. Mask staged as bf16. __launch_bounds__(512,4).
// ---------------------------------------------------------------------------

typedef __attribute__((ext_vector_type(4))) float f32x4;
typedef __attribute__((ext_vector_type(8))) short bf16x8;   // 8 bf16 in 4 VGPRs
typedef __attribute__((ext_vector_type(4))) unsigned int u32x4;
typedef __attribute__((ext_vector_type(2))) unsigned int u32x2;
typedef __attribute__((ext_vector_type(4))) unsigned short u16x4;

#define MFMA16(a, b, c) __builtin_amdgcn_mfma_f32_16x16x32_bf16((a), (b), (c), 0, 0, 0)

union FragAB {
  bf16x8 v;
  ushort u[8];
  u32x4  q4;
  u32x2  q2[2];
};

__device__ __forceinline__ ushort f2b(float f) {
  union { __hip_bfloat16 h; ushort u; } cv;
  cv.h = __float2bfloat16(f);          // native gfx950 cvt, RNE
  return cv.u;
}

__device__ __forceinline__ float b2f(ushort u) {
  union { float f; unsigned int x; } cv;
  cv.x = ((unsigned)u) << 16;
  return cv.f;
}

__device__ __forceinline__ bf16x8 ldfrag(const ushort* p) {   // 16B-aligned
  FragAB f;
  f.q4 = *(const u32x4*)p;
  return f.v;
}

__device__ __forceinline__ bf16x8 ldfrag8(const ushort* p) {  // 8B-aligned rows
  FragAB f;
  f.q2[0] = *(const u32x2*)p;
  f.q2[1] = *(const u32x2*)(p + 4);
  return f.v;
}

__device__ __forceinline__ f32x4 fzero() {
  f32x4 z = {0.0f, 0.0f, 0.0f, 0.0f};
  return z;
}

// ---------------------------------------------------------------------------
// Prep: bf16-convert + MFMA-fragment-repack weights; biasT[h][m][n]; scales.
// Packed weight index: o*256 + kg*32 + lg*8 + e  <->  k = 4lg+e | 16+4lg+(e-4)
// ---------------------------------------------------------------------------
__global__ void prep_kernel(const float* __restrict__ qw, const float* __restrict__ kvw,
                            const float* __restrict__ pw, const float* __restrict__ rpb,
                            const float* __restrict__ lsc,
                            ushort* __restrict__ qwb, ushort* __restrict__ kvwb,
                            ushort* __restrict__ pwb, float* __restrict__ biasT,
                            float* __restrict__ scale) {
  int t = blockIdx.x * blockDim.x + threadIdx.x;
  int stride = gridDim.x * blockDim.x;
  for (int i = t; i < 256 * 256; i += stride) {
    int o = i >> 8, rem = i & 255;
    int kg = rem >> 5, r2 = rem & 31, lg = r2 >> 3, e = r2 & 7;
    int k = (kg << 5) + (lg << 2) + (e < 4 ? e : e + 12);
    qwb[i] = f2b(qw[(o << 8) + k]);
    pwb[i] = f2b(pw[(o << 8) + k]);
  }
  for (int i = t; i < 512 * 256; i += stride) {
    int o = i >> 8, rem = i & 255;
    int kg = rem >> 5, r2 = rem & 31, lg = r2 >> 3, e = r2 & 7;
    int k = (kg << 5) + (lg << 2) + (e < 4 ? e : e + 12);
    kvwb[i] = f2b(kvw[(o << 8) + k]);
  }
  for (int i = t; i < 8 * 64 * 64; i += stride) {
    int h = i >> 12, m = (i >> 6) & 63, n = i & 63;
    int idx = ((n >> 3) - (m >> 3) + 7) * 15 + ((n & 7) - (m & 7) + 7);
    biasT[i] = rpb[idx * 8 + h];
  }
  if (t < 8) scale[t] = __expf(fminf(lsc[t], 4.6051701859880914f));  // log(100)
}

// ---------------------------------------------------------------------------
// Main fused kernel: 512 threads = 8 waves; wave w owns head w / col block w.
// ---------------------------------------------------------------------------
__global__ __launch_bounds__(512, 4)
void wattn_fused(const float* __restrict__ xg, const float* __restrict__ cg,
                 const float* __restrict__ maskg,
                 const float* __restrict__ qb, const float* __restrict__ kvb,
                 const float* __restrict__ pb,
                 const ushort* __restrict__ qwb, const ushort* __restrict__ kvwb,
                 const ushort* __restrict__ pwb,
                 const float* __restrict__ biasT, const float* __restrict__ scaleg,
                 float* __restrict__ outg) {
  // LDS: 33792 + 36864 + 8448 = 79104 B  (<= 80 KiB -> 2 blocks/CU)
  __shared__ __align__(16) ushort xs[64][264];    // x -> c -> att (packed cols)
  __shared__ __align__(16) ushort scr[8][64][36]; // per-wave: q/k transit, vT resident
  __shared__ __align__(16) ushort msb[64][66];    // maskT[m][n], bf16 (0/-100 exact)

  const int b    = blockIdx.x;
  const int wid  = b & 1023;          // window id (b = batch*1024 + w)
  const int tid  = threadIdx.x;
  const int w    = tid >> 6;          // wave / head 0..7
  const int lane = tid & 63;
  const int lg   = lane >> 4;         // 0..3
  const int lc   = lane & 15;         // 0..15
  const int c0   = w << 5;            // this wave's 32-col block base

  ushort (*myscr)[36] = scr[w];                        // [64 tok][32 ch packed + pad]
  ushort (*vscr)[72]  = (ushort(*)[72])&scr[w][0][0];  // [32 d][64 tok packed + pad]

  // ---- Phase A: stage x (f32 -> packed bf16 LDS) + mask (bf16, transposed) ----
  {
    const float4* src = (const float4*)(xg + (size_t)b * 16384);
#pragma unroll
    for (int it = 0; it < 8; ++it) {
      int i = tid + it * 512;
      float4 v = src[i];
      int row = i >> 6;
      int col = (i & 63) << 2;
      ushort* p = &xs[row][(col & ~31) + (((col & 15) >> 2) << 3) + ((col & 16) ? 4 : 0)];
      p[0] = f2b(v.x); p[1] = f2b(v.y); p[2] = f2b(v.z); p[3] = f2b(v.w);
    }
    const float* mp = maskg + (size_t)wid * 4096;
#pragma unroll
    for (int it = 0; it < 8; ++it) {
      int i = tid + it * 512;
      msb[i & 63][i >> 6] = f2b(mp[i]);     // msb[m][n] = mask[w][n][m]
    }
  }
  __syncthreads();

  const int cp0 = ((lc >> 2) << 3) + (lc & 3);   // packed col for chan lc / 16+lc(+4)

  // ---- Phase B: Q = x @ qw^T + qb, per-head L2 norm -> myscr -> qf regs ----
  bf16x8 qf[4];
  {
    f32x4 acc[4][2];
#pragma unroll
    for (int mt = 0; mt < 4; ++mt)
#pragma unroll
      for (int nt = 0; nt < 2; ++nt) acc[mt][nt] = fzero();
#pragma unroll
    for (int kg = 0; kg < 8; ++kg) {
      bf16x8 a[4], bb[2];
#pragma unroll
      for (int mt = 0; mt < 4; ++mt)
        a[mt] = ldfrag(&xs[mt * 16 + lc][(kg << 5) + (lg << 3)]);
#pragma unroll
      for (int nt = 0; nt < 2; ++nt)
        bb[nt] = ldfrag(qwb + ((c0 + nt * 16 + lc) << 8) + (kg << 5) + (lg << 3));
#pragma unroll
      for (int mt = 0; mt < 4; ++mt)
#pragma unroll
        for (int nt = 0; nt < 2; ++nt)
          acc[mt][nt] = MFMA16(a[mt], bb[nt], acc[mt][nt]);
    }
    float bias0 = qb[c0 + lc], bias1 = qb[c0 + 16 + lc];
#pragma unroll
    for (int mt = 0; mt < 4; ++mt) {
#pragma unroll
      for (int reg = 0; reg < 4; ++reg) {
        float v0 = acc[mt][0][reg] + bias0;
        float v1 = acc[mt][1][reg] + bias1;
        float ss = v0 * v0 + v1 * v1;
        ss += __shfl_xor(ss, 1);
        ss += __shfl_xor(ss, 2);
        ss += __shfl_xor(ss, 4);
        ss += __shfl_xor(ss, 8);
        float inv = 1.0f / fmaxf(sqrtf(ss), 1e-12f);
        int row = mt * 16 + (lg << 2) + reg;
        myscr[row][cp0]     = f2b(v0 * inv);
        myscr[row][cp0 + 4] = f2b(v1 * inv);
      }
    }
#pragma unroll
    for (int t4 = 0; t4 < 4; ++t4)
      qf[t4] = ldfrag8(&myscr[t4 * 16 + lc][lg << 3]);   // q B-frags to regs
  }
  __syncthreads();

  // ---- Phase C: stage c over x's buffer ----
  {
    const float4* src = (const float4*)(cg + (size_t)b * 16384);
#pragma unroll
    for (int it = 0; it < 8; ++it) {
      int i = tid + it * 512;
      float4 v = src[i];
      int row = i >> 6;
      int col = (i & 63) << 2;
      ushort* p = &xs[row][(col & ~31) + (((col & 15) >> 2) << 3) + ((col & 16) ? 4 : 0)];
      p[0] = f2b(v.x); p[1] = f2b(v.y); p[2] = f2b(v.z); p[3] = f2b(v.w);
    }
  }
  __syncthreads();

  // ---- Phase D1: K GEMM -> norm -> myscr -> kf regs ----
  bf16x8 kf[4];
  {
    f32x4 acc[4][2];
#pragma unroll
    for (int mt = 0; mt < 4; ++mt)
#pragma unroll
      for (int nt = 0; nt < 2; ++nt) acc[mt][nt] = fzero();
#pragma unroll
    for (int kg = 0; kg < 8; ++kg) {
      bf16x8 a[4], bb[2];
#pragma unroll
      for (int mt = 0; mt < 4; ++mt)
        a[mt] = ldfrag(&xs[mt * 16 + lc][(kg << 5) + (lg << 3)]);
#pragma unroll
      for (int nt = 0; nt < 2; ++nt)
        bb[nt] = ldfrag(kvwb + ((c0 + nt * 16 + lc) << 8) + (kg << 5) + (lg << 3));
#pragma unroll
      for (int mt = 0; mt < 4; ++mt)
#pragma unroll
        for (int nt = 0; nt < 2; ++nt)
          acc[mt][nt] = MFMA16(a[mt], bb[nt], acc[mt][nt]);
    }
    float bias0 = kvb[c0 + lc], bias1 = kvb[c0 + 16 + lc];
#pragma unroll
    for (int mt = 0; mt < 4; ++mt) {
#pragma unroll
      for (int reg = 0; reg < 4; ++reg) {
        float v0 = acc[mt][0][reg] + bias0;
        float v1 = acc[mt][1][reg] + bias1;
        float ss = v0 * v0 + v1 * v1;
        ss += __shfl_xor(ss, 1);
        ss += __shfl_xor(ss, 2);
        ss += __shfl_xor(ss, 4);
        ss += __shfl_xor(ss, 8);
        float inv = 1.0f / fmaxf(sqrtf(ss), 1e-12f);
        int row = mt * 16 + (lg << 2) + reg;
        myscr[row][cp0]     = f2b(v0 * inv);
        myscr[row][cp0 + 4] = f2b(v1 * inv);
      }
    }
#pragma unroll
    for (int t4 = 0; t4 < 4; ++t4)
      kf[t4] = ldfrag8(&myscr[t4 * 16 + lc][lg << 3]);   // k A-frags to regs
  }

  // ---- Phase D2: V GEMM -> vT packed into vscr (overwrites k transit) ----
  {
    f32x4 acc[4][2];
#pragma unroll
    for (int mt = 0; mt < 4; ++mt)
#pragma unroll
      for (int nt = 0; nt < 2; ++nt) acc[mt][nt] = fzero();
#pragma unroll
    for (int kg = 0; kg < 8; ++kg) {
      bf16x8 a[4], bb[2];
#pragma unroll
      for (int mt = 0; mt < 4; ++mt)
        a[mt] = ldfrag(&xs[mt * 16 + lc][(kg << 5) + (lg << 3)]);
#pragma unroll
      for (int nt = 0; nt < 2; ++nt)
        bb[nt] = ldfrag(kvwb + ((256 + c0 + nt * 16 + lc) << 8) + (kg << 5) + (lg << 3));
#pragma unroll
      for (int mt = 0; mt < 4; ++mt)
#pragma unroll
        for (int nt = 0; nt < 2; ++nt)
          acc[mt][nt] = MFMA16(a[mt], bb[nt], acc[mt][nt]);
    }
    float bias0 = kvb[256 + c0 + lc], bias1 = kvb[256 + c0 + 16 + lc];
#pragma unroll
    for (int mt = 0; mt < 4; ++mt) {
      int off = ((mt >> 1) << 5) | (lg << 3) | ((mt & 1) << 2);
      u16x4 pk0, pk1;
#pragma unroll
      for (int reg = 0; reg < 4; ++reg) {
        pk0[reg] = f2b(acc[mt][0][reg] + bias0);
        pk1[reg] = f2b(acc[mt][1][reg] + bias1);
      }
      *(u16x4*)&vscr[lc][off]      = pk0;   // d = lc
      *(u16x4*)&vscr[16 + lc][off] = pk1;   // d = 16+lc
    }
  }

  // ---- Phase E: QK^T (regs) -> softmax -> PV (vscr) ----
  f32x4 ot[2][4];
  {
    const float sc = scaleg[w];
    f32x4 st[4][4];
#pragma unroll
    for (int mt = 0; mt < 4; ++mt)
#pragma unroll
      for (int nt = 0; nt < 4; ++nt) st[mt][nt] = fzero();
#pragma unroll
    for (int mt = 0; mt < 4; ++mt)
#pragma unroll
      for (int nt = 0; nt < 4; ++nt)
        st[mt][nt] = MFMA16(kf[mt], qf[nt], st[mt][nt]);

    // logits + column softmax (reduce over m = rows): in-lane 16 + shfl 16,32
    const float* bT = biasT + (w << 12);
#pragma unroll
    for (int nt = 0; nt < 4; ++nt) {
      int n = nt * 16 + lc;
      float mx = -3.0e38f;
#pragma unroll
      for (int mt = 0; mt < 4; ++mt)
#pragma unroll
        for (int reg = 0; reg < 4; ++reg) {
          int m = mt * 16 + (lg << 2) + reg;
          float val = st[mt][nt][reg] * sc + bT[(m << 6) + n] + b2f(msb[m][n]);
          st[mt][nt][reg] = val;
          mx = fmaxf(mx, val);
        }
      mx = fmaxf(mx, __shfl_xor(mx, 16));
      mx = fmaxf(mx, __shfl_xor(mx, 32));
      float sm = 0.0f;
#pragma unroll
      for (int mt = 0; mt < 4; ++mt)
#pragma unroll
        for (int reg = 0; reg < 4; ++reg) {
          float e = __expf(st[mt][nt][reg] - mx);
          st[mt][nt][reg] = e;
          sm += e;
        }
      sm += __shfl_xor(sm, 16);
      sm += __shfl_xor(sm, 32);
      float inv = 1.0f / sm;
#pragma unroll
      for (int mt = 0; mt < 4; ++mt)
#pragma unroll
        for (int reg = 0; reg < 4; ++reg) st[mt][nt][reg] *= inv;
    }

    // PV: OT[d][n] = sum_m vT[d][m] * Pt[m][n]; P fragments are lane-local.
#pragma unroll
    for (int dmt = 0; dmt < 2; ++dmt)
#pragma unroll
      for (int nt = 0; nt < 4; ++nt) ot[dmt][nt] = fzero();
#pragma unroll
    for (int kt = 0; kt < 2; ++kt) {
      bf16x8 av[2];
#pragma unroll
      for (int dmt = 0; dmt < 2; ++dmt)
        av[dmt] = ldfrag(&vscr[dmt * 16 + lc][(kt << 5) + (lg << 3)]);
#pragma unroll
      for (int nt = 0; nt < 4; ++nt) {
        FragAB bp;
#pragma unroll
        for (int j = 0; j < 4; ++j) {
          bp.u[j]     = f2b(st[2 * kt][nt][j]);
          bp.u[4 + j] = f2b(st[2 * kt + 1][nt][j]);
        }
#pragma unroll
        for (int dmt = 0; dmt < 2; ++dmt)
          ot[dmt][nt] = MFMA16(av[dmt], bp.v, ot[dmt][nt]);
      }
    }
  }
  __syncthreads();   // all waves done reading xs (=c) before att overwrite

  // write attention output into xs (packed cols): att[n][h*32+d]
#pragma unroll
  for (int dmt = 0; dmt < 2; ++dmt)
#pragma unroll
    for (int nt = 0; nt < 4; ++nt)
#pragma unroll
      for (int reg = 0; reg < 4; ++reg) {
        int n = nt * 16 + lc;
        xs[n][c0 + (lg << 3) + reg + (dmt ? 4 : 0)] = f2b(ot[dmt][nt][reg]);
      }
  __syncthreads();

  // ---- Phase F: out = att @ pw^T + pb  (f32 store) ----
  {
    f32x4 acc[4][2];
#pragma unroll
    for (int mt = 0; mt < 4; ++mt)
#pragma unroll
      for (int nt = 0; nt < 2; ++nt) acc[mt][nt] = fzero();
#pragma unroll
    for (int kg = 0; kg < 8; ++kg) {
      bf16x8 a[4], bb[2];
#pragma unroll
      for (int mt = 0; mt < 4; ++mt)
        a[mt] = ldfrag(&xs[mt * 16 + lc][(kg << 5) + (lg << 3)]);
#pragma unroll
      for (int nt = 0; nt < 2; ++nt)
        bb[nt] = ldfrag(pwb + ((c0 + nt * 16 + lc) << 8) + (kg << 5) + (lg << 3));
#pragma unroll
      for (int mt = 0; mt < 4; ++mt)
#pragma unroll
        for (int nt = 0; nt < 2; ++nt)
          acc[mt][nt] = MFMA16(a[mt], bb[nt], acc[mt][nt]);
    }
    float bias0 = pb[c0 + lc], bias1 = pb[c0 + 16 + lc];
    float* op = outg + (size_t)b * 16384;
#pragma unroll
    for (int mt = 0; mt < 4; ++mt) {
#pragma unroll
      for (int reg = 0; reg < 4; ++reg) {
        int row = mt * 16 + (lg << 2) + reg;
        op[(row << 8) + c0 + lc]      = acc[mt][0][reg] + bias0;
        op[(row << 8) + c0 + 16 + lc] = acc[mt][1][reg] + bias1;
      }
    }
  }
}

// ---------------------------------------------------------------------------
extern "C" void kernel_launch(void* const* d_in, const int* in_sizes, int n_in,
                              void* d_out, int out_size, void* d_ws, size_t ws_size,
                              hipStream_t stream) {
  const float* x    = (const float*)d_in[0];
  const float* c    = (const float*)d_in[1];
  const float* mask = (const float*)d_in[2];
  const float* q_w  = (const float*)d_in[3];
  const float* q_b  = (const float*)d_in[4];
  const float* kv_w = (const float*)d_in[5];
  const float* kv_b = (const float*)d_in[6];
  const float* lsc  = (const float*)d_in[7];
  const float* rpb  = (const float*)d_in[8];
  const float* p_w  = (const float*)d_in[9];
  const float* p_b  = (const float*)d_in[10];

  char* ws = (char*)d_ws;
  ushort* qwb   = (ushort*)(ws);                       // 131072 B
  ushort* kvwb  = (ushort*)(ws + 131072);              // 262144 B
  ushort* pwb   = (ushort*)(ws + 131072 + 262144);     // 131072 B
  float*  biasT = (float*)(ws + 524288);               // 131072 B
  float*  scale = (float*)(ws + 524288 + 131072);      // 32 B

  prep_kernel<<<64, 256, 0, stream>>>(q_w, kv_w, p_w, rpb, lsc, qwb, kvwb, pwb, biasT, scale);
  wattn_fused<<<4096, 512, 0, stream>>>(x, c, mask, q_b, kv_b, p_b, qwb, kvwb, pwb,
                                        biasT, scale, (float*)d_out);
}

// Round 3
// 420.082 us; speedup vs baseline: 1.2895x; 1.2895x over previous
//
#include <hip/hip_runtime.h>
#include <hip/hip_bf16.h>

// ---------------------------------------------------------------------------
// Fully-fused SwinV2 window attention, one workgroup per window.
//   B=4096 windows, N=64 tokens, DIM=256, H=8 heads, HD=32, NW=1024 masks.
// Round 3: register-lean Phase E (per-nt QK^T -> softmax -> bf16 P frags) so
// total live regs fit the 128-reg budget of 2 blocks/CU without spills.
// bias2[h][n][m] + untransposed bf16 mask for vectorized softmax loads.
// vT scratch stride 76 (bank-conflict fix), b128 att-output writes.
// ---------------------------------------------------------------------------

typedef __attribute__((ext_vector_type(4))) float f32x4;
typedef __attribute__((ext_vector_type(8))) short bf16x8;   // 8 bf16 in 4 VGPRs
typedef __attribute__((ext_vector_type(4))) unsigned int u32x4;
typedef __attribute__((ext_vector_type(2))) unsigned int u32x2;
typedef __attribute__((ext_vector_type(4))) unsigned short u16x4;

#define MFMA16(a, b, c) __builtin_amdgcn_mfma_f32_16x16x32_bf16((a), (b), (c), 0, 0, 0)

union FragAB {
  bf16x8 v;
  ushort u[8];
  u32x4  q4;
  u32x2  q2[2];
};

__device__ __forceinline__ ushort f2b(float f) {
  union { __hip_bfloat16 h; ushort u; } cv;
  cv.h = __float2bfloat16(f);          // native gfx950 cvt, RNE
  return cv.u;
}

__device__ __forceinline__ float b2f(ushort u) {
  union { float f; unsigned int x; } cv;
  cv.x = ((unsigned)u) << 16;
  return cv.f;
}

__device__ __forceinline__ bf16x8 ldfrag(const ushort* p) {   // 16B-aligned
  FragAB f;
  f.q4 = *(const u32x4*)p;
  return f.v;
}

__device__ __forceinline__ bf16x8 ldfrag8(const ushort* p) {  // 8B-aligned rows
  FragAB f;
  f.q2[0] = *(const u32x2*)p;
  f.q2[1] = *(const u32x2*)(p + 4);
  return f.v;
}

__device__ __forceinline__ f32x4 fzero() {
  f32x4 z = {0.0f, 0.0f, 0.0f, 0.0f};
  return z;
}

// ---------------------------------------------------------------------------
// Prep: bf16-convert + MFMA-fragment-repack weights; bias2[h][n][m]; scales.
// Packed weight index: o*256 + kg*32 + lg*8 + e  <->  k = 4lg+e | 16+4lg+(e-4)
// ---------------------------------------------------------------------------
__global__ void prep_kernel(const float* __restrict__ qw, const float* __restrict__ kvw,
                            const float* __restrict__ pw, const float* __restrict__ rpb,
                            const float* __restrict__ lsc,
                            ushort* __restrict__ qwb, ushort* __restrict__ kvwb,
                            ushort* __restrict__ pwb, float* __restrict__ bias2,
                            float* __restrict__ scale) {
  int t = blockIdx.x * blockDim.x + threadIdx.x;
  int stride = gridDim.x * blockDim.x;
  for (int i = t; i < 256 * 256; i += stride) {
    int o = i >> 8, rem = i & 255;
    int kg = rem >> 5, r2 = rem & 31, lg = r2 >> 3, e = r2 & 7;
    int k = (kg << 5) + (lg << 2) + (e < 4 ? e : e + 12);
    qwb[i] = f2b(qw[(o << 8) + k]);
    pwb[i] = f2b(pw[(o << 8) + k]);
  }
  for (int i = t; i < 512 * 256; i += stride) {
    int o = i >> 8, rem = i & 255;
    int kg = rem >> 5, r2 = rem & 31, lg = r2 >> 3, e = r2 & 7;
    int k = (kg << 5) + (lg << 2) + (e < 4 ? e : e + 12);
    kvwb[i] = f2b(kvw[(o << 8) + k]);
  }
  // bias2[h][n][m] = rpb_table[RPI[n][m]][h]   (n = query, m = key; m fastest)
  for (int i = t; i < 8 * 64 * 64; i += stride) {
    int h = i >> 12, n = (i >> 6) & 63, m = i & 63;
    int idx = ((n >> 3) - (m >> 3) + 7) * 15 + ((n & 7) - (m & 7) + 7);
    bias2[i] = rpb[idx * 8 + h];
  }
  if (t < 8) scale[t] = __expf(fminf(lsc[t], 4.6051701859880914f));  // log(100)
}

// ---------------------------------------------------------------------------
// Main fused kernel: 512 threads = 8 waves; wave w owns head w / col block w.
// ---------------------------------------------------------------------------
__global__ __launch_bounds__(512, 4)
void wattn_fused(const float* __restrict__ xg, const float* __restrict__ cg,
                 const float* __restrict__ maskg,
                 const float* __restrict__ qb, const float* __restrict__ kvb,
                 const float* __restrict__ pb,
                 const ushort* __restrict__ qwb, const ushort* __restrict__ kvwb,
                 const ushort* __restrict__ pwb,
                 const float* __restrict__ bias2, const float* __restrict__ scaleg,
                 float* __restrict__ outg) {
  // LDS: 33792 + 38912 + 8704 = 81408 B (<= 81920 -> 2 blocks/CU)
  __shared__ __align__(16) ushort xs[64][264];    // x -> c -> att (packed cols)
  __shared__ __align__(16) ushort scr[8][2432];   // per-wave q/k transit + vT
  __shared__ __align__(16) ushort msk[64][68];    // mask[n][m], bf16 (0/-100 exact)

  const int b    = blockIdx.x;
  const int wid  = b & 1023;          // window id (b = batch*1024 + w)
  const int tid  = threadIdx.x;
  const int w    = tid >> 6;          // wave / head 0..7
  const int lane = tid & 63;
  const int lg   = lane >> 4;         // 0..3
  const int lc   = lane & 15;         // 0..15
  const int c0   = w << 5;            // this wave's 32-col block base

  ushort (*myscr)[36] = (ushort(*)[36])&scr[w][0];   // [64 tok][32 ch packed]
  ushort (*vscr)[76]  = (ushort(*)[76])&scr[w][0];   // [32 d][64 tok packed + pad]

  // ---- Phase A: stage x (f32 -> packed bf16 LDS) + mask (bf16, [n][m]) ----
  {
    const float4* src = (const float4*)(xg + (size_t)b * 16384);
#pragma unroll
    for (int it = 0; it < 8; ++it) {
      int i = tid + it * 512;
      float4 v = src[i];
      int row = i >> 6;
      int col = (i & 63) << 2;
      ushort* p = &xs[row][(col & ~31) + (((col & 15) >> 2) << 3) + ((col & 16) ? 4 : 0)];
      p[0] = f2b(v.x); p[1] = f2b(v.y); p[2] = f2b(v.z); p[3] = f2b(v.w);
    }
    const float4* mp4 = (const float4*)(maskg + (size_t)wid * 4096);
#pragma unroll
    for (int it = 0; it < 2; ++it) {
      int i = tid + it * 512;
      float4 v = mp4[i];
      u16x4 pk;
      pk[0] = f2b(v.x); pk[1] = f2b(v.y); pk[2] = f2b(v.z); pk[3] = f2b(v.w);
      *(u16x4*)&msk[i >> 4][(i & 15) << 2] = pk;
    }
  }
  __syncthreads();

  const int cp0 = ((lc >> 2) << 3) + (lc & 3);   // packed col for chan lc / 16+lc(+4)

  // ---- Phase B: Q = x @ qw^T + qb, per-head L2 norm -> myscr -> qf regs ----
  bf16x8 qf[4];
  {
    f32x4 acc[4][2];
#pragma unroll
    for (int mt = 0; mt < 4; ++mt)
#pragma unroll
      for (int nt = 0; nt < 2; ++nt) acc[mt][nt] = fzero();
#pragma unroll
    for (int kg = 0; kg < 8; ++kg) {
      bf16x8 a[4], bb[2];
#pragma unroll
      for (int mt = 0; mt < 4; ++mt)
        a[mt] = ldfrag(&xs[mt * 16 + lc][(kg << 5) + (lg << 3)]);
#pragma unroll
      for (int nt = 0; nt < 2; ++nt)
        bb[nt] = ldfrag(qwb + ((c0 + nt * 16 + lc) << 8) + (kg << 5) + (lg << 3));
#pragma unroll
      for (int mt = 0; mt < 4; ++mt)
#pragma unroll
        for (int nt = 0; nt < 2; ++nt)
          acc[mt][nt] = MFMA16(a[mt], bb[nt], acc[mt][nt]);
    }
    float bias0 = qb[c0 + lc], bias1 = qb[c0 + 16 + lc];
#pragma unroll
    for (int mt = 0; mt < 4; ++mt) {
#pragma unroll
      for (int reg = 0; reg < 4; ++reg) {
        float v0 = acc[mt][0][reg] + bias0;
        float v1 = acc[mt][1][reg] + bias1;
        float ss = v0 * v0 + v1 * v1;
        ss += __shfl_xor(ss, 1);
        ss += __shfl_xor(ss, 2);
        ss += __shfl_xor(ss, 4);
        ss += __shfl_xor(ss, 8);
        float inv = 1.0f / fmaxf(sqrtf(ss), 1e-12f);
        int row = mt * 16 + (lg << 2) + reg;
        myscr[row][cp0]     = f2b(v0 * inv);
        myscr[row][cp0 + 4] = f2b(v1 * inv);
      }
    }
#pragma unroll
    for (int t4 = 0; t4 < 4; ++t4)
      qf[t4] = ldfrag8(&myscr[t4 * 16 + lc][lg << 3]);   // q B-frags to regs
  }
  __syncthreads();

  // ---- Phase C: stage c over x's buffer ----
  {
    const float4* src = (const float4*)(cg + (size_t)b * 16384);
#pragma unroll
    for (int it = 0; it < 8; ++it) {
      int i = tid + it * 512;
      float4 v = src[i];
      int row = i >> 6;
      int col = (i & 63) << 2;
      ushort* p = &xs[row][(col & ~31) + (((col & 15) >> 2) << 3) + ((col & 16) ? 4 : 0)];
      p[0] = f2b(v.x); p[1] = f2b(v.y); p[2] = f2b(v.z); p[3] = f2b(v.w);
    }
  }
  __syncthreads();

  // ---- Phase D1: K GEMM -> norm -> myscr -> kf regs ----
  bf16x8 kf[4];
  {
    f32x4 acc[4][2];
#pragma unroll
    for (int mt = 0; mt < 4; ++mt)
#pragma unroll
      for (int nt = 0; nt < 2; ++nt) acc[mt][nt] = fzero();
#pragma unroll
    for (int kg = 0; kg < 8; ++kg) {
      bf16x8 a[4], bb[2];
#pragma unroll
      for (int mt = 0; mt < 4; ++mt)
        a[mt] = ldfrag(&xs[mt * 16 + lc][(kg << 5) + (lg << 3)]);
#pragma unroll
      for (int nt = 0; nt < 2; ++nt)
        bb[nt] = ldfrag(kvwb + ((c0 + nt * 16 + lc) << 8) + (kg << 5) + (lg << 3));
#pragma unroll
      for (int mt = 0; mt < 4; ++mt)
#pragma unroll
        for (int nt = 0; nt < 2; ++nt)
          acc[mt][nt] = MFMA16(a[mt], bb[nt], acc[mt][nt]);
    }
    float bias0 = kvb[c0 + lc], bias1 = kvb[c0 + 16 + lc];
#pragma unroll
    for (int mt = 0; mt < 4; ++mt) {
#pragma unroll
      for (int reg = 0; reg < 4; ++reg) {
        float v0 = acc[mt][0][reg] + bias0;
        float v1 = acc[mt][1][reg] + bias1;
        float ss = v0 * v0 + v1 * v1;
        ss += __shfl_xor(ss, 1);
        ss += __shfl_xor(ss, 2);
        ss += __shfl_xor(ss, 4);
        ss += __shfl_xor(ss, 8);
        float inv = 1.0f / fmaxf(sqrtf(ss), 1e-12f);
        int row = mt * 16 + (lg << 2) + reg;
        myscr[row][cp0]     = f2b(v0 * inv);
        myscr[row][cp0 + 4] = f2b(v1 * inv);
      }
    }
#pragma unroll
    for (int t4 = 0; t4 < 4; ++t4)
      kf[t4] = ldfrag8(&myscr[t4 * 16 + lc][lg << 3]);   // k A-frags to regs
  }

  // ---- Phase D2: V GEMM -> vT packed into vscr (overwrites k transit) ----
  {
    f32x4 acc[4][2];
#pragma unroll
    for (int mt = 0; mt < 4; ++mt)
#pragma unroll
      for (int nt = 0; nt < 2; ++nt) acc[mt][nt] = fzero();
#pragma unroll
    for (int kg = 0; kg < 8; ++kg) {
      bf16x8 a[4], bb[2];
#pragma unroll
      for (int mt = 0; mt < 4; ++mt)
        a[mt] = ldfrag(&xs[mt * 16 + lc][(kg << 5) + (lg << 3)]);
#pragma unroll
      for (int nt = 0; nt < 2; ++nt)
        bb[nt] = ldfrag(kvwb + ((256 + c0 + nt * 16 + lc) << 8) + (kg << 5) + (lg << 3));
#pragma unroll
      for (int mt = 0; mt < 4; ++mt)
#pragma unroll
        for (int nt = 0; nt < 2; ++nt)
          acc[mt][nt] = MFMA16(a[mt], bb[nt], acc[mt][nt]);
    }
    float bias0 = kvb[256 + c0 + lc], bias1 = kvb[256 + c0 + 16 + lc];
#pragma unroll
    for (int mt = 0; mt < 4; ++mt) {
      int off = ((mt >> 1) << 5) | (lg << 3) | ((mt & 1) << 2);
      u16x4 pk0, pk1;
#pragma unroll
      for (int reg = 0; reg < 4; ++reg) {
        pk0[reg] = f2b(acc[mt][0][reg] + bias0);
        pk1[reg] = f2b(acc[mt][1][reg] + bias1);
      }
      *(u16x4*)&vscr[lc][off]      = pk0;   // d = lc
      *(u16x4*)&vscr[16 + lc][off] = pk1;   // d = 16+lc
    }
  }

  // ---- Phase E: per-nt QK^T -> softmax -> bf16 P frags; then PV ----
  u16x4 ov[2][4];
  {
    const float sc = scaleg[w];
    const float* b2 = bias2 + (w << 12);
    FragAB pfr[2][4];            // P fragments, bf16: pfr[kt][nt]
#pragma unroll
    for (int nt = 0; nt < 4; ++nt) {
      f32x4 st[4];
#pragma unroll
      for (int mt = 0; mt < 4; ++mt)
        st[mt] = MFMA16(kf[mt], qf[nt], fzero());
      const int n = nt * 16 + lc;
      float mx = -3.0e38f;
#pragma unroll
      for (int mt = 0; mt < 4; ++mt) {
        f32x4 bv = *(const f32x4*)(b2 + (n << 6) + mt * 16 + (lg << 2));
        u16x4 mk = *(const u16x4*)&msk[n][mt * 16 + (lg << 2)];
#pragma unroll
        for (int reg = 0; reg < 4; ++reg) {
          float val = st[mt][reg] * sc + bv[reg] + b2f(mk[reg]);
          st[mt][reg] = val;
          mx = fmaxf(mx, val);
        }
      }
      mx = fmaxf(mx, __shfl_xor(mx, 16));
      mx = fmaxf(mx, __shfl_xor(mx, 32));
      float sm = 0.0f;
#pragma unroll
      for (int mt = 0; mt < 4; ++mt)
#pragma unroll
        for (int reg = 0; reg < 4; ++reg) {
          float e = __expf(st[mt][reg] - mx);
          st[mt][reg] = e;
          sm += e;
        }
      sm += __shfl_xor(sm, 16);
      sm += __shfl_xor(sm, 32);
      float inv = 1.0f / sm;
#pragma unroll
      for (int kt = 0; kt < 2; ++kt)
#pragma unroll
        for (int j = 0; j < 4; ++j) {
          pfr[kt][nt].u[j]     = f2b(st[2 * kt][j] * inv);
          pfr[kt][nt].u[4 + j] = f2b(st[2 * kt + 1][j] * inv);
        }
    }
    // PV: OT[d][n] = sum_m vT[d][m] * Pt[m][n]; P fragments are lane-local.
    f32x4 ot[2][4];
#pragma unroll
    for (int dmt = 0; dmt < 2; ++dmt)
#pragma unroll
      for (int nt = 0; nt < 4; ++nt) ot[dmt][nt] = fzero();
#pragma unroll
    for (int kt = 0; kt < 2; ++kt) {
      bf16x8 av[2];
#pragma unroll
      for (int dmt = 0; dmt < 2; ++dmt)
        av[dmt] = ldfrag(&vscr[dmt * 16 + lc][(kt << 5) + (lg << 3)]);
#pragma unroll
      for (int nt = 0; nt < 4; ++nt)
#pragma unroll
        for (int dmt = 0; dmt < 2; ++dmt)
          ot[dmt][nt] = MFMA16(av[dmt], pfr[kt][nt].v, ot[dmt][nt]);
    }
    // convert to bf16 before the barrier
#pragma unroll
    for (int dmt = 0; dmt < 2; ++dmt)
#pragma unroll
      for (int nt = 0; nt < 4; ++nt)
#pragma unroll
        for (int reg = 0; reg < 4; ++reg) ov[dmt][nt][reg] = f2b(ot[dmt][nt][reg]);
  }
  __syncthreads();   // all waves done reading xs (=c) before att overwrite

  // write attention output into xs (packed cols): att[n][h*32+d], 16B stores
#pragma unroll
  for (int nt = 0; nt < 4; ++nt) {
    FragAB o8;
    o8.q2[0] = *(u32x2*)&ov[0][nt];
    o8.q2[1] = *(u32x2*)&ov[1][nt];
    *(u32x4*)&xs[nt * 16 + lc][c0 + (lg << 3)] = o8.q4;
  }
  __syncthreads();

  // ---- Phase F: out = att @ pw^T + pb  (f32 store) ----
  {
    f32x4 acc[4][2];
#pragma unroll
    for (int mt = 0; mt < 4; ++mt)
#pragma unroll
      for (int nt = 0; nt < 2; ++nt) acc[mt][nt] = fzero();
#pragma unroll
    for (int kg = 0; kg < 8; ++kg) {
      bf16x8 a[4], bb[2];
#pragma unroll
      for (int mt = 0; mt < 4; ++mt)
        a[mt] = ldfrag(&xs[mt * 16 + lc][(kg << 5) + (lg << 3)]);
#pragma unroll
      for (int nt = 0; nt < 2; ++nt)
        bb[nt] = ldfrag(pwb + ((c0 + nt * 16 + lc) << 8) + (kg << 5) + (lg << 3));
#pragma unroll
      for (int mt = 0; mt < 4; ++mt)
#pragma unroll
        for (int nt = 0; nt < 2; ++nt)
          acc[mt][nt] = MFMA16(a[mt], bb[nt], acc[mt][nt]);
    }
    float bias0 = pb[c0 + lc], bias1 = pb[c0 + 16 + lc];
    float* op = outg + (size_t)b * 16384;
#pragma unroll
    for (int mt = 0; mt < 4; ++mt) {
#pragma unroll
      for (int reg = 0; reg < 4; ++reg) {
        int row = mt * 16 + (lg << 2) + reg;
        op[(row << 8) + c0 + lc]      = acc[mt][0][reg] + bias0;
        op[(row << 8) + c0 + 16 + lc] = acc[mt][1][reg] + bias1;
      }
    }
  }
}

// ---------------------------------------------------------------------------
extern "C" void kernel_launch(void* const* d_in, const int* in_sizes, int n_in,
                              void* d_out, int out_size, void* d_ws, size_t ws_size,
                              hipStream_t stream) {
  const float* x    = (const float*)d_in[0];
  const float* c    = (const float*)d_in[1];
  const float* mask = (const float*)d_in[2];
  const float* q_w  = (const float*)d_in[3];
  const float* q_b  = (const float*)d_in[4];
  const float* kv_w = (const float*)d_in[5];
  const float* kv_b = (const float*)d_in[6];
  const float* lsc  = (const float*)d_in[7];
  const float* rpb  = (const float*)d_in[8];
  const float* p_w  = (const float*)d_in[9];
  const float* p_b  = (const float*)d_in[10];

  char* ws = (char*)d_ws;
  ushort* qwb   = (ushort*)(ws);                       // 131072 B
  ushort* kvwb  = (ushort*)(ws + 131072);              // 262144 B
  ushort* pwb   = (ushort*)(ws + 131072 + 262144);     // 131072 B
  float*  bias2 = (float*)(ws + 524288);               // 131072 B
  float*  scale = (float*)(ws + 524288 + 131072);      // 32 B

  prep_kernel<<<64, 256, 0, stream>>>(q_w, kv_w, p_w, rpb, lsc, qwb, kvwb, pwb, bias2, scale);
  wattn_fused<<<4096, 512, 0, stream>>>(x, c, mask, q_b, kv_b, p_b, qwb, kvwb, pwb,
                                        bias2, scale, (float*)d_out);
}